// Round 7
// baseline (101.008 us; speedup 1.0000x reference)
//
#include <hip/hip_runtime.h>
#include <cstdint>

#define NROWS 50000
#define NCLS  91
#define KPRE  1000
#define NDET  100
#define CAP   4096
#define NBINS 512
#define BIN_OFF 7680u       // bin = (bits>>17) - 7680; scores (0.05,1] -> bins [166,448]
#define LOGCLAMP 4.135166556742356f
#define ROWS_PER_BLOCK 16
#define P1BLK 3125          // 3125*16 = 50000 exactly
#define GCHUNK 128          // greedy: mask rows per LDS chunk

// ---- workspace layout (bytes) ----
constexpr size_t OFF_CNT     = 0;                      // 64 B: [0]=cutoff bin, [1]=compact count
constexpr size_t OFF_ROWMAX  = 64;                     // 50000*2 -> pad to 100096
constexpr size_t OFF_COMPACT = 100096;                 // CAP*8 = 32768
constexpr size_t OFF_SSCORE  = 132864;                 // 1024*4
constexpr size_t OFF_SGIDX   = 136960;                 // 1024*4
constexpr size_t OFF_SLABEL  = 141056;                 // 1024*4
constexpr size_t OFF_BRAW    = 145152;                 // 16384
constexpr size_t OFF_BNMS    = 161536;                 // 16384
constexpr size_t OFF_MASK    = 177920;                 // 1000*16*8 = 128000 -> end ~306 KB

__device__ __forceinline__ bool decode_box(int row, int c,
    const float* __restrict__ regr, const float* __restrict__ props,
    float W, float H, float4& b) {
  const float4 rr = *reinterpret_cast<const float4*>(regr + (size_t)row * (NCLS * 4) + c * 4);
  const float4 pp = *reinterpret_cast<const float4*>(props + (size_t)row * 4);
  float pw = pp.z - pp.x, ph = pp.w - pp.y;
  float cx = pp.x + 0.5f * pw, cy = pp.y + 0.5f * ph;
  float dx = rr.x / 10.0f, dy = rr.y / 10.0f;
  float dw = fminf(rr.z / 5.0f, LOGCLAMP);
  float dh = fminf(rr.w / 5.0f, LOGCLAMP);
  float pcx = dx * pw + cx, pcy = dy * ph + cy;
  float ppw = expf(dw) * pw, pph = expf(dh) * ph;
  float x1 = fminf(fmaxf(pcx - 0.5f * ppw, 0.f), W);
  float y1 = fminf(fmaxf(pcy - 0.5f * pph, 0.f), H);
  float x2 = fminf(fmaxf(pcx + 0.5f * ppw, 0.f), W);
  float y2 = fminf(fmaxf(pcy + 0.5f * pph, 0.f), H);
  b = make_float4(x1, y1, x2, y2);
  return (x2 - x1 >= 0.01f) && (y2 - y1 >= 0.01f);
}

// Pass 1: 16 threads/row, 6 classes/thread. Output: per-row max valid bin ONLY.
// No LDS, no atomics, ~100 KB coalesced writes.
__global__ __launch_bounds__(256)
void pass1_kernel(const float* __restrict__ logits,
                  const float* __restrict__ regr,
                  const float* __restrict__ props,
                  const int* __restrict__ p_imh,
                  const int* __restrict__ p_imw,
                  uint16_t* __restrict__ rowmax) {
  const int gt  = blockIdx.x * 256 + threadIdx.x;
  const int row = gt >> 4;
  const int sub = gt & 15;
  const float* lr = logits + (size_t)row * NCLS;

  float x[6];
  #pragma unroll
  for (int j = 0; j < 6; ++j) {
    int c = sub + 16 * j;
    x[j] = (c < NCLS) ? lr[c] : -INFINITY;
  }
  float m = x[0];
  #pragma unroll
  for (int j = 1; j < 6; ++j) m = fmaxf(m, x[j]);
  m = fmaxf(m, __shfl_xor(m, 1));
  m = fmaxf(m, __shfl_xor(m, 2));
  m = fmaxf(m, __shfl_xor(m, 4));
  m = fmaxf(m, __shfl_xor(m, 8));
  float e[6]; float s = 0.f;
  #pragma unroll
  for (int j = 0; j < 6; ++j) {
    e[j] = (sub + 16 * j < NCLS) ? expf(x[j] - m) : 0.f;
    s += e[j];
  }
  s += __shfl_xor(s, 1);
  s += __shfl_xor(s, 2);
  s += __shfl_xor(s, 4);
  s += __shfl_xor(s, 8);

  const float W = (float)(*p_imw), H = (float)(*p_imh);
  int maxbin = 0;
  #pragma unroll
  for (int j = 0; j < 6; ++j) {
    int c = sub + 16 * j;
    if (c >= 1 && c < NCLS) {
      float score = e[j] / s;
      if (score > 0.05f) {
        float4 b;
        if (decode_box(row, c, regr, props, W, H, b)) {
          uint32_t bin = (__float_as_uint(score) >> 17) - BIN_OFF;
          if ((int)bin > maxbin) maxbin = (int)bin;
        }
      }
    }
  }
  maxbin = max(maxbin, __shfl_xor(maxbin, 1));
  maxbin = max(maxbin, __shfl_xor(maxbin, 2));
  maxbin = max(maxbin, __shfl_xor(maxbin, 4));
  maxbin = max(maxbin, __shfl_xor(maxbin, 8));
  if (sub == 0) rowmax[row] = (uint16_t)maxbin;
}

// 1 block: histogram the 50K rowmax values (LDS), suffix-scan rows ->
// cutoff = largest bin B with #rows(rowmax>=B) >= min(KPRE, totalRows).
// Top-1000 candidates all lie in bins >= B (each such row contributes >=1).
// Also resets the compact counter (no separate memset dispatch).
__global__ __launch_bounds__(512)
void histscan_kernel(const uint16_t* __restrict__ rowmax, uint32_t* __restrict__ cnt) {
  __shared__ uint32_t sh[NBINS];
  const int t = threadIdx.x;
  sh[t] = 0;
  if (t == 0) cnt[1] = 0;
  __syncthreads();
  const uint32_t* r32 = reinterpret_cast<const uint32_t*>(rowmax);
  for (int k = t; k < NROWS / 2; k += 512) {
    uint32_t v = r32[k];
    uint32_t a = v & 0xffffu, b = v >> 16;
    if (a) atomicAdd(&sh[a], 1u);
    if (b) atomicAdd(&sh[b], 1u);
  }
  __syncthreads();
  uint32_t v = sh[t];
  for (int off = 1; off < NBINS; off <<= 1) {
    uint32_t add = (t + off < NBINS) ? sh[t + off] : 0;
    __syncthreads();
    v += add;
    sh[t] = v;
    __syncthreads();
  }
  const uint32_t total = sh[0];
  if (total == 0) { if (t == 0) cnt[0] = 0xFFFFFFFFu; return; }
  const uint32_t target = total < (uint32_t)KPRE ? total : (uint32_t)KPRE;
  const uint32_t rs_t = sh[t];
  const uint32_t rs_n = (t < NBINS - 1) ? sh[t + 1] : 0;
  if (rs_t >= target && rs_n < target) cnt[0] = (uint32_t)t;
}

// Refine: rows with rowmax >= cutoff; 4 rows per wave via 16-lane groups.
// Arithmetic replicates pass1 op-for-op (serial-6 + shfl 1,2,4,8).
__global__ __launch_bounds__(256)
void refine_kernel(const float* __restrict__ logits,
                   const float* __restrict__ regr,
                   const float* __restrict__ props,
                   const int* __restrict__ p_imh,
                   const int* __restrict__ p_imw,
                   const uint16_t* __restrict__ rowmax,
                   uint32_t* __restrict__ cnt,
                   unsigned long long* __restrict__ compact) {
  const int t = threadIdx.x;
  const int lane = t & 63;
  const int g = lane >> 4;
  const int sub = lane & 15;
  const uint32_t cut = cnt[0];
  const int myrow0 = blockIdx.x * 256 + t;
  bool qual = (myrow0 < NROWS) && ((uint32_t)rowmax[myrow0] >= cut);
  unsigned long long bm = __ballot(qual);
  if (!bm) return;
  const int waveBase = blockIdx.x * 256 + (t & ~63);
  const float W = (float)(*p_imw), H = (float)(*p_imh);

  while (bm) {
    int bsel[4];
    #pragma unroll
    for (int k = 0; k < 4; ++k) {
      bsel[k] = bm ? (__ffsll((unsigned long long)bm) - 1) : -1;
      if (bm) bm &= bm - 1;
    }
    const int myb = bsel[g];
    const int row = waveBase + (myb >= 0 ? myb : 0);
    const float* lr = logits + (size_t)row * NCLS;

    float x[6];
    #pragma unroll
    for (int j = 0; j < 6; ++j) {
      int c = sub + 16 * j;
      x[j] = (c < NCLS) ? lr[c] : -INFINITY;
    }
    float m = x[0];
    #pragma unroll
    for (int j = 1; j < 6; ++j) m = fmaxf(m, x[j]);
    m = fmaxf(m, __shfl_xor(m, 1));
    m = fmaxf(m, __shfl_xor(m, 2));
    m = fmaxf(m, __shfl_xor(m, 4));
    m = fmaxf(m, __shfl_xor(m, 8));
    float e[6]; float s = 0.f;
    #pragma unroll
    for (int j = 0; j < 6; ++j) {
      e[j] = (sub + 16 * j < NCLS) ? expf(x[j] - m) : 0.f;
      s += e[j];
    }
    s += __shfl_xor(s, 1);
    s += __shfl_xor(s, 2);
    s += __shfl_xor(s, 4);
    s += __shfl_xor(s, 8);

    if (myb >= 0) {
      #pragma unroll
      for (int j = 0; j < 6; ++j) {
        int c = sub + 16 * j;
        if (c >= 1 && c < NCLS) {
          float score = e[j] / s;
          if (score > 0.05f) {
            float4 bb;
            if (decode_box(row, c, regr, props, W, H, bb)) {
              uint32_t bits = __float_as_uint(score);
              uint32_t bin = (bits >> 17) - BIN_OFF;
              if (bin >= cut) {
                uint32_t pos = atomicAdd(&cnt[1], 1u);
                if (pos < CAP) {
                  uint32_t gidx = (uint32_t)row * 90u + (uint32_t)(c - 1);
                  compact[pos] = ((unsigned long long)bits << 32) |
                                 (unsigned long long)(0xFFFFFFFFu - gidx);
                }
              }
            }
          }
        }
      }
    }
  }
}

// Bitonic sort (width = next pow2 >= count, >=1024) + prep (decode selected).
__global__ __launch_bounds__(1024)
void sort_prep_kernel(const unsigned long long* __restrict__ compact,
                      const uint32_t* __restrict__ cnt,
                      const float* __restrict__ regr, const float* __restrict__ props,
                      const int* __restrict__ p_imh, const int* __restrict__ p_imw,
                      float* __restrict__ sel_score, uint32_t* __restrict__ sel_gidx,
                      int* __restrict__ slabel, float4* __restrict__ braw,
                      float4* __restrict__ bnms) {
  __shared__ unsigned long long arr[CAP];
  const int t = threadIdx.x;
  const uint32_t M = cnt[1] < (uint32_t)CAP ? cnt[1] : (uint32_t)CAP;
  int P = 1024;
  while (P < (int)M) P <<= 1;
  for (int i = t; i < P; i += 1024) arr[i] = (i < (int)M) ? compact[i] : 0ull;
  __syncthreads();
  for (int k = 2; k <= P; k <<= 1) {
    for (int j = k >> 1; j > 0; j >>= 1) {
      for (int i = t; i < P; i += 1024) {
        int l = i ^ j;
        if (l > i) {
          unsigned long long A = arr[i], B = arr[l];
          bool up = ((i & k) == 0);
          if (up ? (A > B) : (A < B)) { arr[i] = B; arr[l] = A; }
        }
      }
      __syncthreads();
    }
  }
  if (t < KPRE) {
    unsigned long long en = arr[P - 1 - t];   // descending
    float sc; uint32_t g;
    if (en) { sc = __uint_as_float((uint32_t)(en >> 32)); g = 0xFFFFFFFFu - (uint32_t)en; }
    else    { sc = -1.f; g = 0xFFFFFFFFu; }
    sel_score[t] = sc;
    sel_gidx[t] = g;
    if (sc > 0.f) {
      int row = (int)(g / 90u);
      int c   = (int)(g % 90u) + 1;
      float W = (float)(*p_imw), H = (float)(*p_imh);
      float4 b;
      decode_box(row, c, regr, props, W, H, b);
      braw[t] = b;
      float offv = (float)c * (float)(*p_imw + *p_imh + 2);
      bnms[t] = make_float4(b.x + offv, b.y + offv, b.z + offv, b.w + offv);
      slabel[t] = c;
    } else {
      braw[t] = make_float4(0, 0, 0, 0);
      bnms[t] = make_float4(0, 0, 0, 0);
      slabel[t] = 0;
    }
  }
}

// 256 threads/block: 4 waves x 4 mask-words each.
__global__ __launch_bounds__(256)
void iou_kernel(const float4* __restrict__ bnms, unsigned long long* __restrict__ mask) {
  const int i = blockIdx.x;
  const int lane = threadIdx.x & 63;
  const int wv = threadIdx.x >> 6;
  const float4 bi = bnms[i];
  const float areai = fmaxf(bi.z - bi.x, 0.f) * fmaxf(bi.w - bi.y, 0.f);
  #pragma unroll
  for (int ww = 0; ww < 4; ++ww) {
    int wd = wv * 4 + ww;
    int j = wd * 64 + lane;
    bool bit = false;
    if (j < KPRE && j > i) {
      float4 bj = bnms[j];
      float areaj = fmaxf(bj.z - bj.x, 0.f) * fmaxf(bj.w - bj.y, 0.f);
      float ltx = fmaxf(bi.x, bj.x), lty = fmaxf(bi.y, bj.y);
      float rbx = fminf(bi.z, bj.z), rby = fminf(bi.w, bj.w);
      float iw = fmaxf(rbx - ltx, 0.f), ih = fmaxf(rby - lty, 0.f);
      float inter = iw * ih;
      float iou = inter / (areai + areaj - inter + 1e-7f);
      bit = iou > 0.5f;
    }
    unsigned long long mword = __ballot(bit);
    if (lane == 0) mask[(size_t)i * 16 + wd] = mword;
  }
}

// Greedy NMS: wave 0 scans from LDS; waves 1-3 prefetch next mask chunk.
__global__ __launch_bounds__(256)
void greedy_kernel(const unsigned long long* __restrict__ mask,
                   const float* __restrict__ sel_score,
                   const int* __restrict__ slabel,
                   const float4* __restrict__ braw,
                   float* __restrict__ out) {
  __shared__ ulonglong2 buf[2][GCHUNK * 8];       // 2 x 16 KB
  __shared__ int kept[NDET];
  __shared__ int s_done;
  const int t = threadIdx.x;
  const int lane = t & 63;
  const int wv = t >> 6;
  const ulonglong2* gm2 = reinterpret_cast<const ulonglong2*>(mask);
  constexpr int NCHUNK = (KPRE + GCHUNK - 1) / GCHUNK;   // 8

  unsigned long long kw = 0ull;
  #pragma unroll
  for (int w = 0; w < 16; ++w) {
    int j = w * 64 + lane;
    bool b = (j < KPRE) && (sel_score[j] > 0.f);
    unsigned long long mword = __ballot(b);
    if (lane == w) kw = mword;
  }
  if (t == 0) s_done = 0;

  {
    int rows = (KPRE < GCHUNK) ? KPRE : GCHUNK;
    int n2 = rows * 8;
    for (int k = t; k < n2; k += 256) buf[0][k] = gm2[k];
  }
  __syncthreads();

  int kc = 0;
  for (int c = 0; c < NCHUNK; ++c) {
    if (wv > 0 && c + 1 < NCHUNK) {
      int rows = KPRE - (c + 1) * GCHUNK;
      if (rows > GCHUNK) rows = GCHUNK;
      int n2 = rows * 8;
      size_t gbase = (size_t)(c + 1) * GCHUNK * 8;
      for (int k = t - 64; k < n2; k += 192) buf[(c + 1) & 1][k] = gm2[gbase + k];
    }
    if (wv == 0) {
      const unsigned long long* bb =
          reinterpret_cast<const unsigned long long*>(buf[c & 1]);
      int rows = KPRE - c * GCHUNK;
      if (rows > GCHUNK) rows = GCHUNK;
      unsigned long long curm = (lane < 16) ? bb[lane] : 0ull;
      for (int r = 0; r < rows; ++r) {
        unsigned long long nxt =
            (lane < 16 && r + 1 < rows) ? bb[(r + 1) * 16 + lane] : 0ull;
        int i = c * GCHUNK + r;
        unsigned long long kwv = __shfl(kw, i >> 6);
        if ((kwv >> (i & 63)) & 1ull) {
          if (lane == 0) kept[kc] = i;
          kw &= ~curm;
          ++kc;
          if (kc >= NDET) { if (lane == 0) s_done = 1; break; }
        }
        curm = nxt;
      }
    }
    __syncthreads();
    if (s_done) break;
  }

  if (wv == 0) {
    for (int q = lane; q < NDET; q += 64) {
      if (q < kc) {
        int i = kept[q];
        float4 b = braw[i];
        out[q * 4 + 0] = b.x; out[q * 4 + 1] = b.y;
        out[q * 4 + 2] = b.z; out[q * 4 + 3] = b.w;
        out[4 * NDET + q] = sel_score[i];
        out[5 * NDET + q] = (float)slabel[i];
      } else {
        out[q * 4 + 0] = 0.f; out[q * 4 + 1] = 0.f;
        out[q * 4 + 2] = 0.f; out[q * 4 + 3] = 0.f;
        out[4 * NDET + q] = 0.f;
        out[5 * NDET + q] = 0.f;
      }
    }
  }
}

extern "C" void kernel_launch(void* const* d_in, const int* in_sizes, int n_in,
                              void* d_out, int out_size, void* d_ws, size_t ws_size,
                              hipStream_t stream) {
  const float* logits = (const float*)d_in[0];
  const float* regr   = (const float*)d_in[1];
  const float* props  = (const float*)d_in[2];
  const int*   p_imh  = (const int*)d_in[3];
  const int*   p_imw  = (const int*)d_in[4];
  float* out = (float*)d_out;

  uint8_t* ws = (uint8_t*)d_ws;
  uint32_t* cnt  = (uint32_t*)(ws + OFF_CNT);
  uint16_t* rowmax = (uint16_t*)(ws + OFF_ROWMAX);
  unsigned long long* compact = (unsigned long long*)(ws + OFF_COMPACT);
  float*    sel_score = (float*)(ws + OFF_SSCORE);
  uint32_t* sel_gidx  = (uint32_t*)(ws + OFF_SGIDX);
  int*      slabel    = (int*)(ws + OFF_SLABEL);
  float4*   braw      = (float4*)(ws + OFF_BRAW);
  float4*   bnms      = (float4*)(ws + OFF_BNMS);
  unsigned long long* mask = (unsigned long long*)(ws + OFF_MASK);

  pass1_kernel<<<P1BLK, 256, 0, stream>>>(
      logits, regr, props, p_imh, p_imw, rowmax);
  histscan_kernel<<<1, NBINS, 0, stream>>>(rowmax, cnt);
  refine_kernel<<<(NROWS + 255) / 256, 256, 0, stream>>>(
      logits, regr, props, p_imh, p_imw, rowmax, cnt, compact);
  sort_prep_kernel<<<1, 1024, 0, stream>>>(compact, cnt, regr, props, p_imh, p_imw,
                                           sel_score, sel_gidx, slabel, braw, bnms);
  iou_kernel<<<KPRE, 256, 0, stream>>>(bnms, mask);
  greedy_kernel<<<1, 256, 0, stream>>>(mask, sel_score, slabel, braw, out);
}